// Round 1
// baseline (413.112 us; speedup 1.0000x reference)
//
#include <hip/hip_runtime.h>

// out = (((x*2 + 3) - 1) / 2)^2  — replicate reference op order exactly for
// bitwise-identical rounding. Pure elementwise, memory-bound.
// 8192*8192 fp32 = 64M elements, divisible by 4 -> float4, no tail handling.

__device__ __forceinline__ float f(float x) {
    float y = ((x * 2.0f + 3.0f) - 1.0f) * 0.5f;  // /2 == *0.5 exactly (power of 2)
    return y * y;
}

__global__ __launch_bounds__(256) void elemwise_kernel(const float4* __restrict__ in,
                                                       float4* __restrict__ out,
                                                       int n4) {
    int i = blockIdx.x * blockDim.x + threadIdx.x;
    if (i < n4) {
        float4 v = in[i];
        float4 r;
        r.x = f(v.x);
        r.y = f(v.y);
        r.z = f(v.z);
        r.w = f(v.w);
        out[i] = r;
    }
}

extern "C" void kernel_launch(void* const* d_in, const int* in_sizes, int n_in,
                              void* d_out, int out_size, void* d_ws, size_t ws_size,
                              hipStream_t stream) {
    const float* x = (const float*)d_in[0];
    float* out = (float*)d_out;
    int n = in_sizes[0];          // 67108864
    int n4 = n / 4;               // divisible: 16777216
    int block = 256;
    int grid = (n4 + block - 1) / block;
    elemwise_kernel<<<grid, block, 0, stream>>>((const float4*)x, (float4*)out, n4);
}